// Round 5
// baseline (277.488 us; speedup 1.0000x reference)
//
#include <hip/hip_runtime.h>

#define GLOBAL_AS __attribute__((address_space(1)))
#define LDS_AS __attribute__((address_space(3)))

typedef unsigned short u16;
typedef unsigned int u32;
typedef __bf16 bf16x8 __attribute__((ext_vector_type(8)));
typedef float f32x4 __attribute__((ext_vector_type(4)));

static constexpr int BB = 8;        // batch
static constexpr int TT = 2048;     // time
static constexpr int DD = 1024;     // feature dim
static constexpr int MM = BB * TT;  // 16384 rows
static constexpr int KK = DD;       // 1024
static constexpr int NC = 64;       // scan chunks per sequence
static constexpr int CL = TT / NC;  // 32 timesteps per chunk
static constexpr int NCH = BB * NC; // 512 total chunks

__device__ __forceinline__ u16 f2bf(float f) {
  union { float f; u32 u; } c; c.f = f;
  u32 u = c.u;
  u32 r = (u + 0x7fffu + ((u >> 16) & 1u)) >> 16;  // RNE
  return (u16)r;
}

__device__ __forceinline__ float bf2f(u16 b) {
  union { u32 u; float f; } c; c.u = ((u32)b) << 16;
  return c.f;
}

// ---------------- pass 0a: x fp32 -> bf16 ----------------
__global__ void cvt_x_kernel(const float* __restrict__ x, u16* __restrict__ xb) {
  int i = (blockIdx.x * blockDim.x + threadIdx.x) * 8;
  const float4* p = reinterpret_cast<const float4*>(x + i);
  float4 v0 = p[0], v1 = p[1];
  u16 r0 = f2bf(v0.x), r1 = f2bf(v0.y), r2 = f2bf(v0.z), r3 = f2bf(v0.w);
  u16 r4 = f2bf(v1.x), r5 = f2bf(v1.y), r6 = f2bf(v1.z), r7 = f2bf(v1.w);
  uint4 o;
  o.x = (u32)r0 | ((u32)r1 << 16);
  o.y = (u32)r2 | ((u32)r3 << 16);
  o.z = (u32)r4 | ((u32)r5 << 16);
  o.w = (u32)r6 | ((u32)r7 << 16);
  *reinterpret_cast<uint4*>(xb + i) = o;
}

// ---------------- pass 0b: W fp32 [k][n] -> bf16 W^T [n][k] ----------------
__global__ void cvt_w_kernel(const float* __restrict__ Wz, const float* __restrict__ Wh,
                             u16* __restrict__ WT) {
  __shared__ float tile[32][33];
  int w = blockIdx.z;
  const float* W = w ? Wh : Wz;
  u16* O = WT + (size_t)w * DD * KK;
  int k0 = blockIdx.y * 32;
  int n0 = blockIdx.x * 32;
  int tx = threadIdx.x, ty = threadIdx.y;
  for (int i = 0; i < 32; i += 8)
    tile[ty + i][tx] = W[(size_t)(k0 + ty + i) * DD + n0 + tx];
  __syncthreads();
  for (int i = 0; i < 32; i += 8)
    O[(size_t)(n0 + ty + i) * KK + k0 + tx] = f2bf(tile[tx][ty + i]);
}

// ---------------- pass 1: dual GEMM + gate epilogue + fused chunk-reduce ----------------
// VERIFIED round-4 structure: 79.9us, MfmaUtil 37%, 0 bank conflicts, no spill.
// (rule #20 lesson: every loop touching accz/acch/Ai/Bi MUST be #pragma unroll --
//  a runtime acc index demotes the whole accumulator to scratch: 2.3GB WRITE_SIZE.)
// DO NOT restructure the main loop (double-buffer regressed via regalloc, r2).
__global__ __launch_bounds__(256, 2) void gemm_dual_kernel(
    const u16* __restrict__ xb,   // [MM][KK] bf16
    const u16* __restrict__ WT,   // [2][DD][KK] bf16 (n-major)
    const float* __restrict__ bz, const float* __restrict__ bh,
    u32* __restrict__ zh_out,     // [MM][DD] packed bf16 pair
    float* __restrict__ Asum, float* __restrict__ Bsum) {
  __shared__ __align__(16) u16 As[128 * 64];
  __shared__ __align__(16) u16 Bzs[128 * 64];
  __shared__ __align__(16) u16 Bhs[128 * 64];

  // XCD-aware swizzle: bid -> swz so XCD x (bid%8==x) gets contiguous swz chunk
  int bid = blockIdx.x;
  int swz = ((bid & 7) << 7) | (bid >> 3);   // bijective (bit permutation)
  int mt = swz >> 3;    // 128 m-tiles
  int nt = swz & 7;     // 8 n-tiles of 128
  int m0 = mt * 128, n0 = nt * 128;

  int tid = threadIdx.x;
  int lane = tid & 63;
  int wave = tid >> 6;
  int wr = wave >> 1;   // wave row 0..1  (owns rows wr*64..wr*64+63)
  int wc = wave & 1;    // wave col 0..1  (owns cols wc*64..wc*64+63)

  // staging: thread's linear LDS dest for issue q is byte  tid*16 + q*4096
  //   -> row r = (tid>>3) + q*32, col-byte = (tid&7)*16, then inverse-swizzled.
  int r0 = tid >> 3;                                    // 0..31
  int cswz = ((tid & 7) ^ ((tid >> 3) & 7)) << 3;       // swizzled col (elems)
  const u16* Ag  = xb + (size_t)(m0 + r0) * KK + cswz;
  const u16* Bzg = WT + (size_t)(n0 + r0) * KK + cswz;
  const u16* Bhg = Bzg + (size_t)DD * KK;

  u16* AsW  = As  + wave * 512;   // wave-uniform base; HW adds lane*16B
  u16* BzsW = Bzs + wave * 512;
  u16* BhsW = Bhs + wave * 512;

  f32x4 accz[4][4];   // [i: 16-row frag][j: 16-col frag]
  f32x4 acch[4][4];
#pragma unroll
  for (int i = 0; i < 4; i++)
#pragma unroll
    for (int j = 0; j < 4; j++) {
      accz[i][j] = (f32x4){0.f, 0.f, 0.f, 0.f};
      acch[i][j] = (f32x4){0.f, 0.f, 0.f, 0.f};
    }

  int fr = lane & 15;
  int fk = (lane >> 4) * 8;
  const int swx = (fr & 7) << 3;   // read-side XOR (elems); row&7 == fr&7 here

  for (int k0i = 0; k0i < KK; k0i += 64) {
#pragma unroll
    for (int q = 0; q < 4; q++) {
      __builtin_amdgcn_global_load_lds((const GLOBAL_AS void*)(Ag  + k0i + (size_t)(q * 32) * KK),
                                       (LDS_AS void*)(AsW + q * 2048), 16, 0, 0);
      __builtin_amdgcn_global_load_lds((const GLOBAL_AS void*)(Bzg + k0i + (size_t)(q * 32) * KK),
                                       (LDS_AS void*)(BzsW + q * 2048), 16, 0, 0);
      __builtin_amdgcn_global_load_lds((const GLOBAL_AS void*)(Bhg + k0i + (size_t)(q * 32) * KK),
                                       (LDS_AS void*)(BhsW + q * 2048), 16, 0, 0);
    }
    __syncthreads();  // drains vmcnt -> staging visible

#pragma unroll
    for (int kk = 0; kk < 64; kk += 32) {
      bf16x8 af[4], bzf[4], bhf[4];
#pragma unroll
      for (int i = 0; i < 4; i++)
        af[i] = *reinterpret_cast<const bf16x8*>(
            As + (wr * 64 + i * 16 + fr) * 64 + ((kk + fk) ^ swx));
#pragma unroll
      for (int j = 0; j < 4; j++) {
        int br = wc * 64 + j * 16 + fr;
        bzf[j] = *reinterpret_cast<const bf16x8*>(Bzs + br * 64 + ((kk + fk) ^ swx));
        bhf[j] = *reinterpret_cast<const bf16x8*>(Bhs + br * 64 + ((kk + fk) ^ swx));
      }
#pragma unroll
      for (int i = 0; i < 4; i++)
#pragma unroll
        for (int j = 0; j < 4; j++) {
          accz[i][j] = __builtin_amdgcn_mfma_f32_16x16x32_bf16(af[i], bzf[j], accz[i][j], 0, 0, 0);
          acch[i][j] = __builtin_amdgcn_mfma_f32_16x16x32_bf16(af[i], bhf[j], acch[i][j], 0, 0, 0);
        }
    }
    __syncthreads();  // tiles consumed before restage
  }

  // epilogue: D[row = m0 + wr*64 + i*16 + quad*4 + r][col = n0 + wc*64 + j*16 + fr]
  // wave owns 64 rows = 2 scan chunks (CL=32): chunk ic composed from i=2ic,2ic+1
  int quad = lane >> 4;
#pragma unroll
  for (int j = 0; j < 4; j++) {
    int n = n0 + wc * 64 + j * 16 + fr;
    float bzv = bz[n], bhv = bh[n];
    float Ai[4], Bi[4];
#pragma unroll
    for (int i = 0; i < 4; i++) {
      float Aloc = 1.f, Bloc = 0.f;
      int mbase = m0 + wr * 64 + i * 16 + quad * 4;
#pragma unroll
      for (int r = 0; r < 4; r++) {
        float zp = accz[i][j][r] + bzv;
        float hp = acch[i][j][r] + bhv;
        u16 zb16 = f2bf(zp);
        u16 hb16 = f2bf(hp);
        size_t idx = (size_t)(mbase + r) * DD + n;
        zh_out[idx] = (u32)zb16 | ((u32)hb16 << 16);
        // compose from the ROUNDED values (consistent with pass 3's reader)
        float zpr = bf2f(zb16);
        float hpr = bf2f(hb16);
        float zs = 1.0f / (1.0f + __expf(-zpr));
        float av = 1.0f - zs;
        float bv = zs * hpr;
        Bloc = av * Bloc + bv;   // t-ascending composition
        Aloc = av * Aloc;
      }
      // ordered cross-quad combine (quads hold rows quad*4..quad*4+3 in the 16-row frag)
      float Ao = __shfl_xor(Aloc, 16, 64);
      float Bo = __shfl_xor(Bloc, 16, 64);
      float Bc = (quad & 1) ? (Aloc * Bo + Bloc) : (Ao * Bloc + Bo);
      float Ac = Aloc * Ao;
      float Ao2 = __shfl_xor(Ac, 32, 64);
      float Bo2 = __shfl_xor(Bc, 32, 64);
      Bi[i] = (quad & 2) ? (Ac * Bo2 + Bc) : (Ao2 * Bc + Bo2);
      Ai[i] = Ac * Ao2;
    }
    // chunk summaries: ic=0 -> frags i0,i1 (rows 0..31), ic=1 -> frags i2,i3
#pragma unroll
    for (int ic = 0; ic < 2; ic++) {
      float Ack = Ai[2 * ic + 1] * Ai[2 * ic];
      float Bck = Ai[2 * ic + 1] * Bi[2 * ic] + Bi[2 * ic + 1];
      if (quad == 0) {
        int cg = mt * 4 + wr * 2 + ic;   // global chunk id = (m0 + wr*64 + ic*32)/32
        Asum[(size_t)cg * DD + n] = Ack;
        Bsum[(size_t)cg * DD + n] = Bck;
      }
    }
  }
}

// ---------------- pass 2: scan over chunk summaries -> h_in per chunk ----------------
// 128 blocks x 64 threads (same 8192 scans) -> spread over 4x more CUs than the
// old 32x256 config; this kernel is latency-bound (64 serial FMA steps).
__global__ __launch_bounds__(64) void chunk_scan_kernel(
    const float* __restrict__ Asum, const float* __restrict__ Bsum,
    float* __restrict__ hin) {
  int tid = blockIdx.x * blockDim.x + threadIdx.x;  // 8192 = [b][d]
  int d = tid & (DD - 1);
  int b = tid >> 10;
  float h = 0.f;
#pragma unroll
  for (int c = 0; c < NC; c++) {
    int i = (b * NC + c) * DD + d;
    hin[i] = h;
    h = Asum[i] * h + Bsum[i];
  }
}

// ---------------- pass 3: apply recurrence + swish + fused LayerNorm ----------------
// WAVE-PER-CHUNK, BARRIER-FREE rewrite: block = 1 wave (64 lanes); lane owns 16 d
// (4x float4 at d = lane*4 + q*256). The 1024-wide LN reduce is now wave-local
// (6 shfl_xor levels) -- removes all 32 per-t __syncthreads + LDS round-trips of
// the old 4-wave version (latency chain that TLP couldn't hide at 2 blocks/CU).
// Depth-2 register prefetch ring keeps HBM saturated; all indices compile-time
// (rule #20).
__global__ __launch_bounds__(64) void apply_ln_kernel(
    const u32* __restrict__ zh, const float* __restrict__ hin,
    const float* __restrict__ sbeta, const float* __restrict__ gamma,
    const float* __restrict__ lbeta, float* __restrict__ out) {
  int ch = blockIdx.x;                 // chunk id 0..511
  int lane = threadIdx.x;              // 0..63
  int d0 = lane * 4;                   // + q*256
  int b = ch >> 6, c = ch & (NC - 1);
  float sb = sbeta[0];

  float4 g4[4], be4[4], h4[4];
#pragma unroll
  for (int q = 0; q < 4; q++) {
    g4[q]  = *reinterpret_cast<const float4*>(gamma + d0 + q * 256);
    be4[q] = *reinterpret_cast<const float4*>(lbeta + d0 + q * 256);
    h4[q]  = *reinterpret_cast<const float4*>(hin + (size_t)ch * DD + d0 + q * 256);
  }

  size_t base = ((size_t)b * TT + (size_t)c * CL) * DD + d0;  // + t*DD + q*256

  // depth-2 prefetch ring (statically indexed after full unroll)
  uint4 zR[2][4];
#pragma unroll
  for (int p = 0; p < 2; p++)
#pragma unroll
    for (int q = 0; q < 4; q++)
      zR[p][q] = *reinterpret_cast<const uint4*>(zh + base + (size_t)p * DD + q * 256);

#pragma unroll
  for (int t = 0; t < CL; t++) {
    const int slot = t & 1;
    uint4 pv[4];
#pragma unroll
    for (int q = 0; q < 4; q++) pv[q] = zR[slot][q];
    if (t + 2 < CL) {   // refill ring; overlaps the math below
#pragma unroll
      for (int q = 0; q < 4; q++)
        zR[slot][q] = *reinterpret_cast<const uint4*>(zh + base + (size_t)(t + 2) * DD + q * 256);
    }
    // unpack + recurrence h = h + sigmoid(zpre)*(hpre - h), then swish
    float4 y[4];
    float sum = 0.f, sq = 0.f;
#pragma unroll
    for (int q = 0; q < 4; q++) {
      union { u32 u; float f; } cz, chh;
      u32 w;
      float zs, s;
      w = pv[q].x; cz.u = w << 16; chh.u = w & 0xffff0000u;
      zs = 1.0f / (1.0f + __expf(-cz.f)); h4[q].x += zs * (chh.f - h4[q].x);
      w = pv[q].y; cz.u = w << 16; chh.u = w & 0xffff0000u;
      zs = 1.0f / (1.0f + __expf(-cz.f)); h4[q].y += zs * (chh.f - h4[q].y);
      w = pv[q].z; cz.u = w << 16; chh.u = w & 0xffff0000u;
      zs = 1.0f / (1.0f + __expf(-cz.f)); h4[q].z += zs * (chh.f - h4[q].z);
      w = pv[q].w; cz.u = w << 16; chh.u = w & 0xffff0000u;
      zs = 1.0f / (1.0f + __expf(-cz.f)); h4[q].w += zs * (chh.f - h4[q].w);
      s = sb * h4[q].x; y[q].x = s / (1.0f + __expf(-s));
      s = sb * h4[q].y; y[q].y = s / (1.0f + __expf(-s));
      s = sb * h4[q].z; y[q].z = s / (1.0f + __expf(-s));
      s = sb * h4[q].w; y[q].w = s / (1.0f + __expf(-s));
      sum += y[q].x + y[q].y + y[q].z + y[q].w;
      sq  += y[q].x * y[q].x + y[q].y * y[q].y + y[q].z * y[q].z + y[q].w * y[q].w;
    }
    // wave-local 1024-wide reduce: 6 xor levels, no LDS, no barrier
#pragma unroll
    for (int o = 32; o > 0; o >>= 1) {
      sum += __shfl_xor(sum, o, 64);
      sq  += __shfl_xor(sq, o, 64);
    }
    float mu = sum * (1.0f / DD);
    float var = sq * (1.0f / DD) - mu * mu;
    float inv = rsqrtf(fmaxf(var, 0.f) + 1e-5f);
#pragma unroll
    for (int q = 0; q < 4; q++) {
      float4 o4;
      o4.x = (y[q].x - mu) * inv * g4[q].x + be4[q].x;
      o4.y = (y[q].y - mu) * inv * g4[q].y + be4[q].y;
      o4.z = (y[q].z - mu) * inv * g4[q].z + be4[q].z;
      o4.w = (y[q].w - mu) * inv * g4[q].w + be4[q].w;
      *reinterpret_cast<float4*>(out + base + (size_t)t * DD + q * 256) = o4;
    }
  }
}

extern "C" void kernel_launch(void* const* d_in, const int* in_sizes, int n_in,
                              void* d_out, int out_size, void* d_ws, size_t ws_size,
                              hipStream_t stream) {
  const float* x     = (const float*)d_in[0];
  const float* Wz    = (const float*)d_in[1];
  const float* bz    = (const float*)d_in[2];
  const float* Wh    = (const float*)d_in[3];
  const float* bh    = (const float*)d_in[4];
  const float* sbeta = (const float*)d_in[5];
  const float* gamma = (const float*)d_in[6];
  const float* lbeta = (const float*)d_in[7];
  float* out = (float*)d_out;

  char* ws = (char*)d_ws;
  u16* xb     = (u16*)ws;                         // 33,554,432 B
  u16* WT     = (u16*)(ws + 33554432);            //  4,194,304 B
  u32* zh     = (u32*)(ws + 37748736);            // 67,108,864 B (packed bf16 z|h)
  float* Asum = (float*)(ws + 104857600);         //  2,097,152 B
  float* Bsum = (float*)(ws + 106954752);         //  2,097,152 B
  float* hin  = (float*)(ws + 109051904);         //  2,097,152 B  (total 111,149,056)

  cvt_x_kernel<<<8192, 256, 0, stream>>>(x, xb);
  dim3 tw(32, 8), gw(32, 32, 2);
  cvt_w_kernel<<<gw, tw, 0, stream>>>(Wz, Wh, WT);
  gemm_dual_kernel<<<1024, 256, 0, stream>>>(xb, WT, bz, bh, zh, Asum, Bsum);
  chunk_scan_kernel<<<128, 64, 0, stream>>>(Asum, Bsum, hin);
  apply_ln_kernel<<<NCH, 64, 0, stream>>>(zh, hin, sbeta, gamma, lbeta, out);
}

// Round 6
// 234.044 us; speedup vs baseline: 1.1856x; 1.1856x over previous
//
#include <hip/hip_runtime.h>

#define GLOBAL_AS __attribute__((address_space(1)))
#define LDS_AS __attribute__((address_space(3)))

typedef unsigned short u16;
typedef unsigned int u32;
typedef __bf16 bf16x8 __attribute__((ext_vector_type(8)));
typedef float f32x4 __attribute__((ext_vector_type(4)));

static constexpr int BB = 8;        // batch
static constexpr int TT = 2048;     // time
static constexpr int DD = 1024;     // feature dim
static constexpr int MM = BB * TT;  // 16384 rows
static constexpr int KK = DD;       // 1024
static constexpr int NC = 64;       // scan chunks per sequence
static constexpr int CL = TT / NC;  // 32 timesteps per chunk
static constexpr int NCH = BB * NC; // 512 total chunks

__device__ __forceinline__ u16 f2bf(float f) {
  union { float f; u32 u; } c; c.f = f;
  u32 u = c.u;
  u32 r = (u + 0x7fffu + ((u >> 16) & 1u)) >> 16;  // RNE
  return (u16)r;
}

__device__ __forceinline__ float bf2f(u16 b) {
  union { u32 u; float f; } c; c.u = ((u32)b) << 16;
  return c.f;
}

// ---------------- pass 0a: x fp32 -> bf16 ----------------
__global__ void cvt_x_kernel(const float* __restrict__ x, u16* __restrict__ xb) {
  int i = (blockIdx.x * blockDim.x + threadIdx.x) * 8;
  const float4* p = reinterpret_cast<const float4*>(x + i);
  float4 v0 = p[0], v1 = p[1];
  u16 r0 = f2bf(v0.x), r1 = f2bf(v0.y), r2 = f2bf(v0.z), r3 = f2bf(v0.w);
  u16 r4 = f2bf(v1.x), r5 = f2bf(v1.y), r6 = f2bf(v1.z), r7 = f2bf(v1.w);
  uint4 o;
  o.x = (u32)r0 | ((u32)r1 << 16);
  o.y = (u32)r2 | ((u32)r3 << 16);
  o.z = (u32)r4 | ((u32)r5 << 16);
  o.w = (u32)r6 | ((u32)r7 << 16);
  *reinterpret_cast<uint4*>(xb + i) = o;
}

// ---------------- pass 0b: W fp32 [k][n] -> bf16 W^T [n][k] ----------------
__global__ void cvt_w_kernel(const float* __restrict__ Wz, const float* __restrict__ Wh,
                             u16* __restrict__ WT) {
  __shared__ float tile[32][33];
  int w = blockIdx.z;
  const float* W = w ? Wh : Wz;
  u16* O = WT + (size_t)w * DD * KK;
  int k0 = blockIdx.y * 32;
  int n0 = blockIdx.x * 32;
  int tx = threadIdx.x, ty = threadIdx.y;
  for (int i = 0; i < 32; i += 8)
    tile[ty + i][tx] = W[(size_t)(k0 + ty + i) * DD + n0 + tx];
  __syncthreads();
  for (int i = 0; i < 32; i += 8)
    O[(size_t)(n0 + ty + i) * KK + k0 + tx] = f2bf(tile[tx][ty + i]);
}

// ---------------- pass 1: dual GEMM + gate epilogue + fused chunk-reduce ----------------
// VERIFIED round-4 structure: 79.9us, MfmaUtil 37%, 0 bank conflicts, no spill.
// (rule #20 lesson: every loop touching accz/acch/Ai/Bi MUST be #pragma unroll --
//  a runtime acc index demotes the whole accumulator to scratch: 2.3GB WRITE_SIZE.)
// DO NOT restructure the main loop (double-buffer regressed via regalloc, r2).
// Round-6 change: pack (a fixed-u16 | b bf16) instead of (zpre|hpre). The gate
// sigmoid is already computed here for the chunk summaries; storing a,b directly
// removes 4 exp + 4 rcp + 4 sub per lane per t from apply_ln (r1->r4 showed the
// sigmoid-recompute reader cost +27us; apply_ln is VALU/latency-bound, not BW).
// a in 16-bit fixed point: err 1.5e-5 (BETTER than bf16 zpre's ~1e-3 gate err).
__global__ __launch_bounds__(256, 2) void gemm_dual_kernel(
    const u16* __restrict__ xb,   // [MM][KK] bf16
    const u16* __restrict__ WT,   // [2][DD][KK] bf16 (n-major)
    const float* __restrict__ bz, const float* __restrict__ bh,
    u32* __restrict__ ab_out,     // [MM][DD] packed: lo16 = a*65535, hi16 = bf16(b)
    float* __restrict__ Asum, float* __restrict__ Bsum) {
  __shared__ __align__(16) u16 As[128 * 64];
  __shared__ __align__(16) u16 Bzs[128 * 64];
  __shared__ __align__(16) u16 Bhs[128 * 64];

  // XCD-aware swizzle: bid -> swz so XCD x (bid%8==x) gets contiguous swz chunk
  int bid = blockIdx.x;
  int swz = ((bid & 7) << 7) | (bid >> 3);   // bijective (bit permutation)
  int mt = swz >> 3;    // 128 m-tiles
  int nt = swz & 7;     // 8 n-tiles of 128
  int m0 = mt * 128, n0 = nt * 128;

  int tid = threadIdx.x;
  int lane = tid & 63;
  int wave = tid >> 6;
  int wr = wave >> 1;   // wave row 0..1  (owns rows wr*64..wr*64+63)
  int wc = wave & 1;    // wave col 0..1  (owns cols wc*64..wc*64+63)

  // staging: thread's linear LDS dest for issue q is byte  tid*16 + q*4096
  //   -> row r = (tid>>3) + q*32, col-byte = (tid&7)*16, then inverse-swizzled.
  int r0 = tid >> 3;                                    // 0..31
  int cswz = ((tid & 7) ^ ((tid >> 3) & 7)) << 3;       // swizzled col (elems)
  const u16* Ag  = xb + (size_t)(m0 + r0) * KK + cswz;
  const u16* Bzg = WT + (size_t)(n0 + r0) * KK + cswz;
  const u16* Bhg = Bzg + (size_t)DD * KK;

  u16* AsW  = As  + wave * 512;   // wave-uniform base; HW adds lane*16B
  u16* BzsW = Bzs + wave * 512;
  u16* BhsW = Bhs + wave * 512;

  f32x4 accz[4][4];   // [i: 16-row frag][j: 16-col frag]
  f32x4 acch[4][4];
#pragma unroll
  for (int i = 0; i < 4; i++)
#pragma unroll
    for (int j = 0; j < 4; j++) {
      accz[i][j] = (f32x4){0.f, 0.f, 0.f, 0.f};
      acch[i][j] = (f32x4){0.f, 0.f, 0.f, 0.f};
    }

  int fr = lane & 15;
  int fk = (lane >> 4) * 8;
  const int swx = (fr & 7) << 3;   // read-side XOR (elems); row&7 == fr&7 here

  for (int k0i = 0; k0i < KK; k0i += 64) {
#pragma unroll
    for (int q = 0; q < 4; q++) {
      __builtin_amdgcn_global_load_lds((const GLOBAL_AS void*)(Ag  + k0i + (size_t)(q * 32) * KK),
                                       (LDS_AS void*)(AsW + q * 2048), 16, 0, 0);
      __builtin_amdgcn_global_load_lds((const GLOBAL_AS void*)(Bzg + k0i + (size_t)(q * 32) * KK),
                                       (LDS_AS void*)(BzsW + q * 2048), 16, 0, 0);
      __builtin_amdgcn_global_load_lds((const GLOBAL_AS void*)(Bhg + k0i + (size_t)(q * 32) * KK),
                                       (LDS_AS void*)(BhsW + q * 2048), 16, 0, 0);
    }
    __syncthreads();  // drains vmcnt -> staging visible

#pragma unroll
    for (int kk = 0; kk < 64; kk += 32) {
      bf16x8 af[4], bzf[4], bhf[4];
#pragma unroll
      for (int i = 0; i < 4; i++)
        af[i] = *reinterpret_cast<const bf16x8*>(
            As + (wr * 64 + i * 16 + fr) * 64 + ((kk + fk) ^ swx));
#pragma unroll
      for (int j = 0; j < 4; j++) {
        int br = wc * 64 + j * 16 + fr;
        bzf[j] = *reinterpret_cast<const bf16x8*>(Bzs + br * 64 + ((kk + fk) ^ swx));
        bhf[j] = *reinterpret_cast<const bf16x8*>(Bhs + br * 64 + ((kk + fk) ^ swx));
      }
#pragma unroll
      for (int i = 0; i < 4; i++)
#pragma unroll
        for (int j = 0; j < 4; j++) {
          accz[i][j] = __builtin_amdgcn_mfma_f32_16x16x32_bf16(af[i], bzf[j], accz[i][j], 0, 0, 0);
          acch[i][j] = __builtin_amdgcn_mfma_f32_16x16x32_bf16(af[i], bhf[j], acch[i][j], 0, 0, 0);
        }
    }
    __syncthreads();  // tiles consumed before restage
  }

  // epilogue: D[row = m0 + wr*64 + i*16 + quad*4 + r][col = n0 + wc*64 + j*16 + fr]
  // wave owns 64 rows = 2 scan chunks (CL=32): chunk ic composed from i=2ic,2ic+1
  int quad = lane >> 4;
#pragma unroll
  for (int j = 0; j < 4; j++) {
    int n = n0 + wc * 64 + j * 16 + fr;
    float bzv = bz[n], bhv = bh[n];
    float Ai[4], Bi[4];
#pragma unroll
    for (int i = 0; i < 4; i++) {
      float Aloc = 1.f, Bloc = 0.f;
      int mbase = m0 + wr * 64 + i * 16 + quad * 4;
#pragma unroll
      for (int r = 0; r < 4; r++) {
        float zp = accz[i][j][r] + bzv;
        float hp = acch[i][j][r] + bhv;
        float zs = 1.0f / (1.0f + __expf(-zp));
        float av = 1.0f - zs;
        float bv = zs * hp;
        // pack: a as 16-bit fixed point (err 1.5e-5), b as bf16
        u32 aq = (u32)(av * 65535.0f + 0.5f);
        if (aq > 65535u) aq = 65535u;
        u16 bb16 = f2bf(bv);
        size_t idx = (size_t)(mbase + r) * DD + n;
        ab_out[idx] = aq | ((u32)bb16 << 16);
        // compose from the ROUNDED values (consistent with pass 3's reader)
        float avr = (float)aq * (1.0f / 65535.0f);
        float bvr = bf2f(bb16);
        Bloc = avr * Bloc + bvr;   // t-ascending composition
        Aloc = avr * Aloc;
      }
      // ordered cross-quad combine (quads hold rows quad*4..quad*4+3 in the 16-row frag)
      float Ao = __shfl_xor(Aloc, 16, 64);
      float Bo = __shfl_xor(Bloc, 16, 64);
      float Bc = (quad & 1) ? (Aloc * Bo + Bloc) : (Ao * Bloc + Bo);
      float Ac = Aloc * Ao;
      float Ao2 = __shfl_xor(Ac, 32, 64);
      float Bo2 = __shfl_xor(Bc, 32, 64);
      Bi[i] = (quad & 2) ? (Ac * Bo2 + Bc) : (Ao2 * Bc + Bo2);
      Ai[i] = Ac * Ao2;
    }
    // chunk summaries: ic=0 -> frags i0,i1 (rows 0..31), ic=1 -> frags i2,i3
#pragma unroll
    for (int ic = 0; ic < 2; ic++) {
      float Ack = Ai[2 * ic + 1] * Ai[2 * ic];
      float Bck = Ai[2 * ic + 1] * Bi[2 * ic] + Bi[2 * ic + 1];
      if (quad == 0) {
        int cg = mt * 4 + wr * 2 + ic;   // global chunk id = (m0 + wr*64 + ic*32)/32
        Asum[(size_t)cg * DD + n] = Ack;
        Bsum[(size_t)cg * DD + n] = Bck;
      }
    }
  }
}

// ---------------- pass 2: scan over chunk summaries -> h_in per chunk ----------------
__global__ void chunk_scan_kernel(const float* __restrict__ Asum, const float* __restrict__ Bsum,
                                  float* __restrict__ hin) {
  int tid = blockIdx.x * blockDim.x + threadIdx.x;  // 8192 = [b][d]
  int d = tid & (DD - 1);
  int b = tid >> 10;
  float h = 0.f;
#pragma unroll
  for (int c = 0; c < NC; c++) {
    int i = (b * NC + c) * DD + d;
    hin[i] = h;
    h = Asum[i] * h + Bsum[i];
  }
}

// ---------------- pass 3: apply recurrence + swish + fused LayerNorm ----------------
// Round-4 structure (PROVEN best: 4 waves/block, 512 blocks = 2048 waves = 2/SIMD;
// the r5 wave-per-chunk rewrite capped the chip at 512 waves and lost 32us --
// TLP > barrier removal here). Reader is now LEAN: unpack a (and+cvt+mul) and
// b (mask+bitcast), h = a*h + b -- no sigmoid recompute (that cost r4 +27us).
__global__ __launch_bounds__(256) void apply_ln_kernel(
    const u32* __restrict__ ab, const float* __restrict__ hin,
    const float* __restrict__ sbeta, const float* __restrict__ gamma,
    const float* __restrict__ lbeta, float* __restrict__ out) {
  __shared__ float ps[2][4];
  __shared__ float pq[2][4];
  int ch = blockIdx.x;                 // chunk id 0..511
  int wv = threadIdx.x >> 6;
  int lane = threadIdx.x & 63;
  int d = wv * 256 + lane * 4;
  int b = ch >> 6, c = ch & (NC - 1);
  float sb = sbeta[0];

  float4 g4 = *reinterpret_cast<const float4*>(gamma + d);
  float4 be4 = *reinterpret_cast<const float4*>(lbeta + d);
  float4 h4 = *reinterpret_cast<const float4*>(hin + (size_t)ch * DD + d);

  size_t base = ((size_t)b * TT + (size_t)c * CL) * DD + d;  // + t*DD

  // depth-3 prefetch ring (statically indexed after full unroll)
  uint4 zR[3];
#pragma unroll
  for (int p = 0; p < 3; p++)
    zR[p] = *reinterpret_cast<const uint4*>(ab + base + (size_t)p * DD);

#pragma unroll
  for (int t = 0; t < CL; t++) {
    const int slot = t % 3;
    const int pslot = t & 1;
    uint4 pv = zR[slot];
    if (t + 3 < CL)   // refill ring; overlaps the math below
      zR[slot] = *reinterpret_cast<const uint4*>(ab + base + (size_t)(t + 3) * DD);
    // unpack + recurrence: h = a*h + b   (a = lo16/65535, b = bf16 in hi16)
    {
      union { u32 u; float f; } cb;
      const float as = 1.0f / 65535.0f;
      float av;
      av = (float)(pv.x & 0xffffu) * as; cb.u = pv.x & 0xffff0000u;
      h4.x = av * h4.x + cb.f;
      av = (float)(pv.y & 0xffffu) * as; cb.u = pv.y & 0xffff0000u;
      h4.y = av * h4.y + cb.f;
      av = (float)(pv.z & 0xffffu) * as; cb.u = pv.z & 0xffff0000u;
      h4.z = av * h4.z + cb.f;
      av = (float)(pv.w & 0xffffu) * as; cb.u = pv.w & 0xffff0000u;
      h4.w = av * h4.w + cb.f;
    }
    float sx = sb * h4.x, sy = sb * h4.y, sz = sb * h4.z, sw = sb * h4.w;
    float4 y;
    y.x = sx / (1.0f + __expf(-sx));
    y.y = sy / (1.0f + __expf(-sy));
    y.z = sz / (1.0f + __expf(-sz));
    y.w = sw / (1.0f + __expf(-sw));
    float sum = y.x + y.y + y.z + y.w;
    float sq = y.x * y.x + y.y * y.y + y.z * y.z + y.w * y.w;
#pragma unroll
    for (int o = 32; o > 0; o >>= 1) {
      sum += __shfl_xor(sum, o, 64);
      sq += __shfl_xor(sq, o, 64);
    }
    if (lane == 0) { ps[pslot][wv] = sum; pq[pslot][wv] = sq; }
    __syncthreads();
    float tot = ps[pslot][0] + ps[pslot][1] + ps[pslot][2] + ps[pslot][3];
    float totq = pq[pslot][0] + pq[pslot][1] + pq[pslot][2] + pq[pslot][3];
    float mu = tot * (1.0f / DD);
    float var = totq * (1.0f / DD) - mu * mu;
    float inv = rsqrtf(fmaxf(var, 0.f) + 1e-5f);
    float4 o4;
    o4.x = (y.x - mu) * inv * g4.x + be4.x;
    o4.y = (y.y - mu) * inv * g4.y + be4.y;
    o4.z = (y.z - mu) * inv * g4.z + be4.z;
    o4.w = (y.w - mu) * inv * g4.w + be4.w;
    *reinterpret_cast<float4*>(out + base + (size_t)t * DD) = o4;
  }
}

extern "C" void kernel_launch(void* const* d_in, const int* in_sizes, int n_in,
                              void* d_out, int out_size, void* d_ws, size_t ws_size,
                              hipStream_t stream) {
  const float* x     = (const float*)d_in[0];
  const float* Wz    = (const float*)d_in[1];
  const float* bz    = (const float*)d_in[2];
  const float* Wh    = (const float*)d_in[3];
  const float* bh    = (const float*)d_in[4];
  const float* sbeta = (const float*)d_in[5];
  const float* gamma = (const float*)d_in[6];
  const float* lbeta = (const float*)d_in[7];
  float* out = (float*)d_out;

  char* ws = (char*)d_ws;
  u16* xb     = (u16*)ws;                         // 33,554,432 B
  u16* WT     = (u16*)(ws + 33554432);            //  4,194,304 B
  u32* ab     = (u32*)(ws + 37748736);            // 67,108,864 B (packed a|b)
  float* Asum = (float*)(ws + 104857600);         //  2,097,152 B
  float* Bsum = (float*)(ws + 106954752);         //  2,097,152 B
  float* hin  = (float*)(ws + 109051904);         //  2,097,152 B  (total 111,149,056)

  cvt_x_kernel<<<8192, 256, 0, stream>>>(x, xb);
  dim3 tw(32, 8), gw(32, 32, 2);
  cvt_w_kernel<<<gw, tw, 0, stream>>>(Wz, Wh, WT);
  gemm_dual_kernel<<<1024, 256, 0, stream>>>(xb, WT, bz, bh, ab, Asum, Bsum);
  chunk_scan_kernel<<<32, 256, 0, stream>>>(Asum, Bsum, hin);
  apply_ln_kernel<<<NCH, 256, 0, stream>>>(ab, hin, sbeta, gamma, lbeta, out);
}